// Round 8
// baseline (68.495 us; speedup 1.0000x reference)
//
#include <hip/hip_runtime.h>
#include <math.h>

#define NTHR 256
#define B_ 4
#define F_ 512
#define N_ 1024
#define V_ 4
#define NPTS (B_ * F_ * N_)          // 2097152
#define GSTR (F_ * N_)               // 524288 = points per batch (loop stride)
#define NBLK (GSTR / NTHR)           // 2048 blocks, 4 pts/thread (one per batch)

struct Partial {                     // 64 B, all f32
  float sum_diff2, sum_dist, sum_acc2, cnt;
  float gmin[3], gmax[3], pmin[3], pmax[3];
};

__global__ __launch_bounds__(NTHR, 8) void loss_main(
    const float* __restrict__ pred, const float* __restrict__ gt,
    const int* __restrict__ vis, const float* __restrict__ P,
    const float* __restrict__ tracks, Partial* __restrict__ partials)
{
  __shared__ float sP[B_ * V_ * 12];          // all 16 mats (each block sees all b)
  __shared__ Partial sw[NTHR / 64];

  // XCD swizzle: 2048 blocks -> 256 consecutive blocks per XCD (bijective)
  const int bid = ((blockIdx.x & 7) << 8) + (blockIdx.x >> 3);
  const int t = threadIdx.x;
  const int g = (bid << 8) + t;               // point within batch [0, 524288)
  const int f = g >> 10;                      // wave-uniform (256 | 1024)

  if (t < B_ * V_ * 12) sP[t] = P[t];         // P is [V][B][3][4] = 192 floats
  __syncthreads();

  // loop-invariant pieces
  const int d1 = (f + 1 < F_) ? N_ : 0;       // clamped neighbor offsets (points)
  const int d2 = (f + 2 < F_) ? 2 * N_ : 0;
  const float am = (f < F_ - 2) ? 1.0f : 0.0f;

  float sum_diff2 = 0.0f, sum_dist = 0.0f, sum_acc2 = 0.0f, cntf = 0.0f;
  float gmin[3] = { INFINITY,  INFINITY,  INFINITY};
  float gmax[3] = {-INFINITY, -INFINITY, -INFINITY};
  float pmin[3] = { INFINITY,  INFINITY,  INFINITY};
  float pmax[3] = {-INFINITY, -INFINITY, -INFINITY};

  for (int b = 0; b < B_; ++b) {              // stride = one full batch
    const size_t e = (size_t)b * GSTR + g;    // point id

    // ---- all loads up front, independent, coalesced
    const float* pp = pred + e * 3;
    const float px = pp[0], py = pp[1], pz = pp[2];

    const float* gp = gt + e * 3;
    const float gx = gp[0], gy = gp[1], gz = gp[2];

    const int vm = vis[e];

    const float* q1 = pred + (e + d1) * 3;
    const float n1x = q1[0], n1y = q1[1], n1z = q1[2];
    const float* q2 = pred + (e + d2) * 3;
    const float n2x = q2[0], n2y = q2[1], n2z = q2[2];

    const float2 tk0 = *(const float2*)(tracks + ((((size_t)(0 * B_ + b) << 19) + g) << 1));
    const float2 tk1 = *(const float2*)(tracks + ((((size_t)(1 * B_ + b) << 19) + g) << 1));
    const float2 tk2 = *(const float2*)(tracks + ((((size_t)(2 * B_ + b) << 19) + g) << 1));
    const float2 tk3 = *(const float2*)(tracks + ((((size_t)(3 * B_ + b) << 19) + g) << 1));

    // ---- compute (branchless)
    const float vmf = vm ? 1.0f : 0.0f;
    const float dd0 = px - gx, dd1 = py - gy, dd2 = pz - gz;
    sum_diff2 += vmf * (dd0 * dd0 + dd1 * dd1 + dd2 * dd2);
    cntf += vmf;
    gmin[0] = fminf(gmin[0], vm ? gx :  INFINITY);
    gmax[0] = fmaxf(gmax[0], vm ? gx : -INFINITY);
    gmin[1] = fminf(gmin[1], vm ? gy :  INFINITY);
    gmax[1] = fmaxf(gmax[1], vm ? gy : -INFINITY);
    gmin[2] = fminf(gmin[2], vm ? gz :  INFINITY);
    gmax[2] = fmaxf(gmax[2], vm ? gz : -INFINITY);
    pmin[0] = fminf(pmin[0], px); pmax[0] = fmaxf(pmax[0], px);
    pmin[1] = fminf(pmin[1], py); pmax[1] = fmaxf(pmax[1], py);
    pmin[2] = fminf(pmin[2], pz); pmax[2] = fmaxf(pmax[2], pz);

    const float a0 = n2x - 2.0f * n1x + px;
    const float a1 = n2y - 2.0f * n1y + py;
    const float a2 = n2z - 2.0f * n1z + pz;
    sum_acc2 += am * (a0 * a0 + a1 * a1 + a2 * a2);

    const float2 tks[V_] = {tk0, tk1, tk2, tk3};
#pragma unroll
    for (int v = 0; v < V_; ++v) {
      const float* Pm = sP + (v * B_ + b) * 12;
      const float h0 = Pm[0] * px + Pm[1] * py + Pm[2]  * pz + Pm[3];
      const float h1 = Pm[4] * px + Pm[5] * py + Pm[6]  * pz + Pm[7];
      const float h2 = Pm[8] * px + Pm[9] * py + Pm[10] * pz + Pm[11];
      const float inv = __builtin_amdgcn_rcpf(h2 + 1e-10f);
      const float dx = h0 * inv - tks[v].x;
      const float dy = h1 * inv - tks[v].y;
      sum_dist += dx * dx + dy * dy;
    }
  }

  // ---- wave shuffle reduction (deterministic tree), amortized over 4 pts
#pragma unroll
  for (int o = 32; o > 0; o >>= 1) {
    sum_diff2 += __shfl_down(sum_diff2, o);
    sum_dist  += __shfl_down(sum_dist,  o);
    sum_acc2  += __shfl_down(sum_acc2,  o);
    cntf      += __shfl_down(cntf,      o);
#pragma unroll
    for (int k = 0; k < 3; ++k) {
      gmin[k] = fminf(gmin[k], __shfl_down(gmin[k], o));
      gmax[k] = fmaxf(gmax[k], __shfl_down(gmax[k], o));
      pmin[k] = fminf(pmin[k], __shfl_down(pmin[k], o));
      pmax[k] = fmaxf(pmax[k], __shfl_down(pmax[k], o));
    }
  }

  const int wave = t >> 6, lane = t & 63;
  if (lane == 0) {
    Partial p;
    p.sum_diff2 = sum_diff2; p.sum_dist = sum_dist;
    p.sum_acc2  = sum_acc2;  p.cnt      = cntf;
#pragma unroll
    for (int k = 0; k < 3; ++k) {
      p.gmin[k] = gmin[k]; p.gmax[k] = gmax[k];
      p.pmin[k] = pmin[k]; p.pmax[k] = pmax[k];
    }
    sw[wave] = p;
  }
  __syncthreads();
  if (t == 0) {
    Partial p = sw[0];
#pragma unroll
    for (int w = 1; w < NTHR / 64; ++w) {
      p.sum_diff2 += sw[w].sum_diff2; p.sum_dist += sw[w].sum_dist;
      p.sum_acc2  += sw[w].sum_acc2;  p.cnt      += sw[w].cnt;
#pragma unroll
      for (int k = 0; k < 3; ++k) {
        p.gmin[k] = fminf(p.gmin[k], sw[w].gmin[k]);
        p.gmax[k] = fmaxf(p.gmax[k], sw[w].gmax[k]);
        p.pmin[k] = fminf(p.pmin[k], sw[w].pmin[k]);
        p.pmax[k] = fmaxf(p.pmax[k], sw[w].pmax[k]);
      }
    }
    partials[bid] = p;
  }
}

__global__ __launch_bounds__(NTHR) void loss_final(
    const Partial* __restrict__ partials, float* __restrict__ out)
{
  float sum_diff2 = 0.0f, sum_dist = 0.0f, sum_acc2 = 0.0f, cnt = 0.0f;
  float gmin[3] = { INFINITY,  INFINITY,  INFINITY};
  float gmax[3] = {-INFINITY, -INFINITY, -INFINITY};
  float pmin[3] = { INFINITY,  INFINITY,  INFINITY};
  float pmax[3] = {-INFINITY, -INFINITY, -INFINITY};

  const int tid = threadIdx.x;
  for (int i = tid; i < NBLK; i += NTHR) {   // fixed order -> deterministic
    const Partial p = partials[i];
    sum_diff2 += p.sum_diff2; sum_dist += p.sum_dist;
    sum_acc2  += p.sum_acc2;  cnt      += p.cnt;
#pragma unroll
    for (int k = 0; k < 3; ++k) {
      gmin[k] = fminf(gmin[k], p.gmin[k]); gmax[k] = fmaxf(gmax[k], p.gmax[k]);
      pmin[k] = fminf(pmin[k], p.pmin[k]); pmax[k] = fmaxf(pmax[k], p.pmax[k]);
    }
  }

#pragma unroll
  for (int o = 32; o > 0; o >>= 1) {
    sum_diff2 += __shfl_down(sum_diff2, o);
    sum_dist  += __shfl_down(sum_dist,  o);
    sum_acc2  += __shfl_down(sum_acc2,  o);
    cnt       += __shfl_down(cnt,       o);
#pragma unroll
    for (int k = 0; k < 3; ++k) {
      gmin[k] = fminf(gmin[k], __shfl_down(gmin[k], o));
      gmax[k] = fmaxf(gmax[k], __shfl_down(gmax[k], o));
      pmin[k] = fminf(pmin[k], __shfl_down(pmin[k], o));
      pmax[k] = fmaxf(pmax[k], __shfl_down(pmax[k], o));
    }
  }

  __shared__ Partial sw[NTHR / 64];
  const int lane = tid & 63;
  const int wave = tid >> 6;
  if (lane == 0) {
    Partial p;
    p.sum_diff2 = sum_diff2; p.sum_dist = sum_dist;
    p.sum_acc2  = sum_acc2;  p.cnt      = cnt;
#pragma unroll
    for (int k = 0; k < 3; ++k) {
      p.gmin[k] = gmin[k]; p.gmax[k] = gmax[k];
      p.pmin[k] = pmin[k]; p.pmax[k] = pmax[k];
    }
    sw[wave] = p;
  }
  __syncthreads();

  if (tid == 0) {
    Partial p = sw[0];
#pragma unroll
    for (int w = 1; w < NTHR / 64; ++w) {
      p.sum_diff2 += sw[w].sum_diff2; p.sum_dist += sw[w].sum_dist;
      p.sum_acc2  += sw[w].sum_acc2;  p.cnt      += sw[w].cnt;
#pragma unroll
      for (int k = 0; k < 3; ++k) {
        p.gmin[k] = fminf(p.gmin[k], sw[w].gmin[k]);
        p.gmax[k] = fmaxf(p.gmax[k], sw[w].gmax[k]);
        p.pmin[k] = fminf(p.pmin[k], sw[w].pmin[k]);
        p.pmax[k] = fmaxf(p.pmax[k], sw[w].pmax[k]);
      }
    }

    double sr = -INFINITY;
#pragma unroll
    for (int k = 0; k < 3; ++k) sr = fmax(sr, (double)p.gmax[k] - (double)p.gmin[k]);
    sr += 1e-6;
    const double recon = (double)p.sum_diff2 / fmax((double)p.cnt * 3.0, 1.0) / (sr * sr);

    const double ident = (double)p.sum_dist / 224.0 / ((double)V_ * B_ * F_ * N_ * 2.0);

    double st = -INFINITY;
#pragma unroll
    for (int k = 0; k < 3; ++k) st = fmax(st, (double)p.pmax[k] - (double)p.pmin[k]);
    st += 1e-6;
    const double tloss = (double)p.sum_acc2 / ((double)B_ * (F_ - 2) * N_);
    const double temp = tloss / (st * st);

    const double total = recon + ident + 0.5 * temp;
    out[0] = (float)total;
    out[1] = (float)recon;
    out[2] = (float)ident;
    out[3] = (float)temp;
  }
}

extern "C" void kernel_launch(void* const* d_in, const int* in_sizes, int n_in,
                              void* d_out, int out_size, void* d_ws, size_t ws_size,
                              hipStream_t stream) {
  const float* pred   = (const float*)d_in[0];
  const float* gt     = (const float*)d_in[1];
  const int*   vis    = (const int*)d_in[2];
  const float* P      = (const float*)d_in[3];
  const float* tracks = (const float*)d_in[4];
  float* out = (float*)d_out;
  Partial* partials = (Partial*)d_ws;   // 2048 * 64 B = 128 KB

  loss_main<<<NBLK, NTHR, 0, stream>>>(pred, gt, vis, P, tracks, partials);
  loss_final<<<1, NTHR, 0, stream>>>(partials, out);
}